// Round 3
// baseline (604.185 us; speedup 1.0000x reference)
//
#include <hip/hip_runtime.h>
#include <hip/hip_bf16.h>

// GAT forward: N=8192, IN=512, HID=256, OUT=64.
// w_ij = A_ij * max( e^{s1_i} e^{s2_j}, e^{0.2 s1_i} e^{0.2 s2_j} )
// Round 3: k_attn reads B-fragments DIRECTLY from L2 (no LDS, no barriers);
// ks = bid&3 pins each 1MB H1TB slice to XCDs; each wave owns 64 hid x both
// 16-row groups (1x L2 traffic). packA/h1/ws-zero fused into one fat kernel.

typedef float f32x4 __attribute__((ext_vector_type(4)));
typedef short s16x8 __attribute__((ext_vector_type(8)));

#define NN 8192
#define INDIM 512
#define HIDD 256
#define OUTD 64

static __device__ __forceinline__ short f2bf(float x) {
    __hip_bfloat16 h = __float2bfloat16(x);
    return __builtin_bit_cast(short, h);
}

static __device__ __forceinline__ void split_bf(float x, short& hi, short& lo) {
    short h = f2bf(x);
    unsigned int hb = ((unsigned int)(unsigned short)h) << 16;
    float hf = __builtin_bit_cast(float, hb);
    hi = h;
    lo = f2bf(x - hf);
}

// ---------------- kernel 0: W1 (512x256 f32) -> W1^T hi/lo bf16 [256][512] -------------
__global__ void k_splitW1(const float* __restrict__ W1,
                          short* __restrict__ W1Thi, short* __restrict__ W1Tlo) {
    int t = blockIdx.x * 256 + threadIdx.x;   // t = n*512 + k
    int n = t >> 9;
    int k = t & 511;
    float x = W1[k * 256 + n];
    short hi, lo; split_bf(x, hi, lo);
    W1Thi[t] = hi;
    W1Tlo[t] = lo;
}

// ---------------- fat kernel: h1 (512) || packA (2048, 4 rows ea) || zeroWS (128) ------
// h1: H1 = X@W1+b1 (split-bf16 MFMA), writes tile-contiguous bf16 H1TB + exp factors.
// packA: A (8192x8192 int32) -> bitmask, dword i*256 + ks*64 + q*16 + kk4,
//        byte kkq, bit j  <->  col = ks*2048 + (kk4*4+kkq)*32 + q*8 + j.
// zeroWS: Zw + H2acc (8,421,376 B contiguous) = 526336 float4, 4112 per block.
__global__ void __launch_bounds__(256)
k_fat(const float* __restrict__ X, const short* __restrict__ W1Thi,
      const short* __restrict__ W1Tlo, const float* __restrict__ b1,
      const float* __restrict__ avec, unsigned short* __restrict__ H1TB,
      float* __restrict__ alw, float* __restrict__ bew, float* __restrict__ uvw,
      const int* __restrict__ A, unsigned int* __restrict__ Apk,
      float* __restrict__ Zw) {
    __shared__ float s1p[4][16];
    __shared__ float s2p[4][16];
    const int b = blockIdx.x;
    const int tid = threadIdx.x;

    if (b >= 2560) {                       // ---- zeroWS part ----
        f32x4 z4 = {0.f, 0.f, 0.f, 0.f};
        f32x4* dst = (f32x4*)Zw + (size_t)(b - 2560) * 4112;
        for (int t = tid; t < 4112; t += 256) dst[t] = z4;
        return;
    }

    if (b >= 512) {                        // ---- packA part: 4 rows ----
        const int i0 = (b - 512) * 4;
        const int ks = tid >> 6, q = (tid >> 4) & 3, kk0 = tid & 15;
#pragma unroll
        for (int r = 0; r < 4; ++r) {
            const int i = i0 + r;
            const int* Ar = A + (size_t)i * NN;
            unsigned int out = 0;
#pragma unroll
            for (int kkq = 0; kkq < 4; ++kkq) {
                const int kk = kk0 * 4 + kkq;
                const int c0 = ks * 2048 + kk * 32 + q * 8;
                int4 v0 = *(const int4*)(Ar + c0);
                int4 v1 = *(const int4*)(Ar + c0 + 4);
                unsigned int bb = 0;
                bb |= (v0.x > 0) ? 1u : 0u;
                bb |= (v0.y > 0) ? 2u : 0u;
                bb |= (v0.z > 0) ? 4u : 0u;
                bb |= (v0.w > 0) ? 8u : 0u;
                bb |= (v1.x > 0) ? 16u : 0u;
                bb |= (v1.y > 0) ? 32u : 0u;
                bb |= (v1.z > 0) ? 64u : 0u;
                bb |= (v1.w > 0) ? 128u : 0u;
                out |= bb << (kkq * 8);
            }
            Apk[(size_t)i * 256 + tid] = out;
        }
        return;
    }

    // ---- h1 part (blocks 0..511) ----
    const int wn = tid >> 6, lane = tid & 63;
    const int q = lane >> 4, m16 = lane & 15;
    const int i0 = b * 16;
    const int irow = i0 + m16;

    f32x4 zero4 = {0.f, 0.f, 0.f, 0.f};
    f32x4 acc[4];
#pragma unroll
    for (int nt = 0; nt < 4; ++nt) acc[nt] = zero4;

    const float* Xrow = X + (size_t)irow * INDIM;
    for (int kk = 0; kk < INDIM; kk += 32) {
        const int k0 = kk + q * 8;
        float4 xa = *(const float4*)(Xrow + k0);
        float4 xb = *(const float4*)(Xrow + k0 + 4);
        float xs[8] = {xa.x, xa.y, xa.z, xa.w, xb.x, xb.y, xb.z, xb.w};
        s16x8 ahi, alo;
#pragma unroll
        for (int j = 0; j < 8; ++j) { short h, l; split_bf(xs[j], h, l); ahi[j] = h; alo[j] = l; }
#pragma unroll
        for (int nt = 0; nt < 4; ++nt) {
            const int n = wn * 64 + nt * 16 + m16;
            s16x8 bhi = *(const s16x8*)(W1Thi + n * INDIM + k0);
            s16x8 blo = *(const s16x8*)(W1Tlo + n * INDIM + k0);
            acc[nt] = __builtin_amdgcn_mfma_f32_16x16x32_bf16(ahi, bhi, acc[nt], 0, 0, 0);
            acc[nt] = __builtin_amdgcn_mfma_f32_16x16x32_bf16(ahi, blo, acc[nt], 0, 0, 0);
            acc[nt] = __builtin_amdgcn_mfma_f32_16x16x32_bf16(alo, bhi, acc[nt], 0, 0, 0);
        }
    }

    float p1[4] = {0.f, 0.f, 0.f, 0.f};
    float p2[4] = {0.f, 0.f, 0.f, 0.f};
    const int rowbase = i0 + q * 4;
    const int chunk = rowbase >> 5, win = rowbase & 31;
#pragma unroll
    for (int nt = 0; nt < 4; ++nt) {
        const int col = wn * 64 + nt * 16 + m16;
        const float b1v = b1[col];
        const float a1v = avec[col];
        const float a2v = avec[HIDD + col];
        float v0 = acc[nt][0] + b1v;
        float v1 = acc[nt][1] + b1v;
        float v2 = acc[nt][2] + b1v;
        float v3 = acc[nt][3] + b1v;
        ushort4 us;
        us.x = (unsigned short)f2bf(v0);
        us.y = (unsigned short)f2bf(v1);
        us.z = (unsigned short)f2bf(v2);
        us.w = (unsigned short)f2bf(v3);
        *(ushort4*)(H1TB + (size_t)chunk * 8192 + col * 32 + win) = us;
        p1[0] += v0 * a1v; p1[1] += v1 * a1v; p1[2] += v2 * a1v; p1[3] += v3 * a1v;
        p2[0] += v0 * a2v; p2[1] += v1 * a2v; p2[2] += v2 * a2v; p2[3] += v3 * a2v;
    }
#pragma unroll
    for (int off = 1; off < 16; off <<= 1) {
#pragma unroll
        for (int r = 0; r < 4; ++r) {
            p1[r] += __shfl_xor(p1[r], off);
            p2[r] += __shfl_xor(p2[r], off);
        }
    }
    if (m16 == 0) {
#pragma unroll
        for (int r = 0; r < 4; ++r) {
            s1p[wn][q * 4 + r] = p1[r];
            s2p[wn][q * 4 + r] = p2[r];
        }
    }
    __syncthreads();
    if (tid < 16) {
        const int i = i0 + tid;
        float s1 = s1p[0][tid] + s1p[1][tid] + s1p[2][tid] + s1p[3][tid];
        float s2 = s2p[0][tid] + s2p[1][tid] + s2p[2][tid] + s2p[3][tid];
        alw[i] = expf(s1);
        bew[i] = expf(0.2f * s1);
        uvw[2 * i]     = expf(s2);
        uvw[2 * i + 1] = expf(0.2f * s2);
    }
}

// ---------------- kernel 2: H2acc += W @ H1 (barrier-free, L2-direct bf16 MFMA) --------
// Grid 1024: ks = bid&3 (pins each 1MB H1TB slice per XCD), mb = bid>>2 (32 rows).
// 4 waves: wave wn owns hid [wn*64, wn*64+64) x BOTH 16-row groups. B-fragments
// read straight from L2 (contiguous 1KB per wave per nt), depth-1 reg prefetch.
// No LDS, no __syncthreads, no vmcnt games - waves fully independent.
__global__ void __launch_bounds__(256, 4)
k_attn(const unsigned int* __restrict__ Apk, const unsigned short* __restrict__ H1TB,
       const float* __restrict__ alw, const float* __restrict__ bew,
       const float* __restrict__ uvw,
       float* __restrict__ H2acc, float* __restrict__ Zw) {
    const int tid = threadIdx.x;
    const int wn = tid >> 6, lane = tid & 63;
    const int q = lane >> 4, m16 = lane & 15;
    const int ks = blockIdx.x & 3;
    const int mb = blockIdx.x >> 2;
    const int i0 = mb * 32 + m16;          // row-group 0
    const int i1 = i0 + 16;                // row-group 1
    const float al0 = alw[i0], be0 = bew[i0];
    const float al1 = alw[i1], be1 = bew[i1];

    const size_t hslice = (size_t)ks * 64 * 8192;          // ushort units
    const int lbase = (wn * 64 + m16) * 32 + q * 8;
    const unsigned int* Ab0 = Apk + (size_t)i0 * 256 + ks * 64 + q * 16;
    const unsigned int* Ab1 = Apk + (size_t)i1 * 256 + ks * 64 + q * 16;
    const float* uvp = uvw + 2 * (ks * 2048 + q * 8);

    f32x4 zero4 = {0.f, 0.f, 0.f, 0.f};
    f32x4 acc0[4], acc1[4];
#pragma unroll
    for (int nt = 0; nt < 4; ++nt) { acc0[nt] = zero4; acc1[nt] = zero4; }
    float zacc0 = 0.f, zacc1 = 0.f;

    // prologue: B(0), uv(0), A dwords 0
    s16x8 bA[4], bB[4];
#pragma unroll
    for (int nt = 0; nt < 4; ++nt)
        bA[nt] = *(const s16x8*)(H1TB + hslice + lbase + nt * 512);
    float4 uv0 = *(const float4*)(uvp);
    float4 uv1 = *(const float4*)(uvp + 4);
    float4 uv2 = *(const float4*)(uvp + 8);
    float4 uv3 = *(const float4*)(uvp + 12);
    uvp += 64;
    unsigned int a40 = Ab0[0], a41 = Ab1[0];

    // One K-step: wv-gen(kk) -> prefetch uv(kk+1),B(kk+1) -> MFMA(kk) on BC.
    // kk=63 prefetches chunk 64 / uv 2048: lands in adjacent workspace, unused.
#define STEP(BC, BN, KK, KKQ)                                                          \
    {                                                                                  \
        const unsigned int ab0 = a40 >> ((KKQ) * 8);                                   \
        const unsigned int ab1 = a41 >> ((KKQ) * 8);                                   \
        float w0[8], w1[8];                                                            \
        w0[0] = (ab0 & 1u)   ? fmaxf(al0 * uv0.x, be0 * uv0.y) : 0.f;                  \
        w0[1] = (ab0 & 2u)   ? fmaxf(al0 * uv0.z, be0 * uv0.w) : 0.f;                  \
        w0[2] = (ab0 & 4u)   ? fmaxf(al0 * uv1.x, be0 * uv1.y) : 0.f;                  \
        w0[3] = (ab0 & 8u)   ? fmaxf(al0 * uv1.z, be0 * uv1.w) : 0.f;                  \
        w0[4] = (ab0 & 16u)  ? fmaxf(al0 * uv2.x, be0 * uv2.y) : 0.f;                  \
        w0[5] = (ab0 & 32u)  ? fmaxf(al0 * uv2.z, be0 * uv2.w) : 0.f;                  \
        w0[6] = (ab0 & 64u)  ? fmaxf(al0 * uv3.x, be0 * uv3.y) : 0.f;                  \
        w0[7] = (ab0 & 128u) ? fmaxf(al0 * uv3.z, be0 * uv3.w) : 0.f;                  \
        w1[0] = (ab1 & 1u)   ? fmaxf(al1 * uv0.x, be1 * uv0.y) : 0.f;                  \
        w1[1] = (ab1 & 2u)   ? fmaxf(al1 * uv0.z, be1 * uv0.w) : 0.f;                  \
        w1[2] = (ab1 & 4u)   ? fmaxf(al1 * uv1.x, be1 * uv1.y) : 0.f;                  \
        w1[3] = (ab1 & 8u)   ? fmaxf(al1 * uv1.z, be1 * uv1.w) : 0.f;                  \
        w1[4] = (ab1 & 16u)  ? fmaxf(al1 * uv2.x, be1 * uv2.y) : 0.f;                  \
        w1[5] = (ab1 & 32u)  ? fmaxf(al1 * uv2.z, be1 * uv2.w) : 0.f;                  \
        w1[6] = (ab1 & 64u)  ? fmaxf(al1 * uv3.x, be1 * uv3.y) : 0.f;                  \
        w1[7] = (ab1 & 128u) ? fmaxf(al1 * uv3.z, be1 * uv3.w) : 0.f;                  \
        zacc0 += (w0[0] + w0[1] + w0[2] + w0[3]) + (w0[4] + w0[5] + w0[6] + w0[7]);    \
        zacc1 += (w1[0] + w1[1] + w1[2] + w1[3]) + (w1[4] + w1[5] + w1[6] + w1[7]);    \
        s16x8 af0, af1;                                                                \
        _Pragma("unroll")                                                              \
        for (int j = 0; j < 8; ++j) { af0[j] = f2bf(w0[j]); af1[j] = f2bf(w1[j]); }    \
        uv0 = *(const float4*)(uvp);                                                   \
        uv1 = *(const float4*)(uvp + 4);                                               \
        uv2 = *(const float4*)(uvp + 8);                                               \
        uv3 = *(const float4*)(uvp + 12);                                              \
        uvp += 64;                                                                     \
        {                                                                              \
            const unsigned short* hq = H1TB + hslice + (size_t)((KK) + 1) * 8192 + lbase; \
            _Pragma("unroll")                                                          \
            for (int nt = 0; nt < 4; ++nt) BN[nt] = *(const s16x8*)(hq + nt * 512);    \
        }                                                                              \
        _Pragma("unroll")                                                              \
        for (int nt = 0; nt < 4; ++nt) {                                               \
            acc0[nt] = __builtin_amdgcn_mfma_f32_16x16x32_bf16(af0, BC[nt], acc0[nt], 0, 0, 0); \
            acc1[nt] = __builtin_amdgcn_mfma_f32_16x16x32_bf16(af1, BC[nt], acc1[nt], 0, 0, 0); \
        }                                                                              \
    }

    for (int kk4 = 0; kk4 < 16; ++kk4) {
        const unsigned int a40n = Ab0[(kk4 + 1) & 15];
        const unsigned int a41n = Ab1[(kk4 + 1) & 15];
        const int kb = kk4 * 4;
        STEP(bA, bB, kb + 0, 0)
        STEP(bB, bA, kb + 1, 1)
        STEP(bA, bB, kb + 2, 2)
        STEP(bB, bA, kb + 3, 3)
        a40 = a40n;
        a41 = a41n;
    }
#undef STEP

    // Z row-sums: reduce over q; wave 0 only; one atomic per row-group per row.
    zacc0 += __shfl_xor(zacc0, 16);
    zacc0 += __shfl_xor(zacc0, 32);
    zacc1 += __shfl_xor(zacc1, 16);
    zacc1 += __shfl_xor(zacc1, 32);
    if (wn == 0 && q == 0) {
        atomicAdd(&Zw[i0], zacc0);
        atomicAdd(&Zw[i1], zacc1);
    }

    const int r0 = mb * 32 + q * 4;
#pragma unroll
    for (int nt = 0; nt < 4; ++nt) {
        const int col = wn * 64 + nt * 16 + m16;
#pragma unroll
        for (int r = 0; r < 4; ++r) {
            atomicAdd(&H2acc[(size_t)(r0 + r) * HIDD + col], acc0[nt][r]);
            atomicAdd(&H2acc[(size_t)(r0 + 16 + r) * HIDD + col], acc1[nt][r]);
        }
    }
}

// ---------------- kernel 3: out = sigmoid((H2acc/Z) @ Omega + beta) --------------------
__global__ void __launch_bounds__(256)
k_out(const float* __restrict__ H2acc, const float* __restrict__ Zw,
      const float* __restrict__ Omega, const float* __restrict__ beta,
      float* __restrict__ out) {
    __shared__ float om[HIDD * OUTD];  // 64 KB
    const int tid = threadIdx.x;
    for (int idx = tid; idx < HIDD * OUTD; idx += 256) om[idx] = Omega[idx];
    __syncthreads();
    const int wave = tid >> 6, o = tid & 63;
    const float bv = beta[o];
    for (int rr = 0; rr < 8; ++rr) {
        const int i = blockIdx.x * 32 + wave * 8 + rr;
        const float4* H2v = (const float4*)(H2acc + (size_t)i * HIDD);
        float acc = 0.f;
#pragma unroll 4
        for (int c4 = 0; c4 < 64; ++c4) {
            float4 h = H2v[c4];
            const int cb = c4 * 4;
            acc = fmaf(h.x, om[(cb + 0) * OUTD + o], acc);
            acc = fmaf(h.y, om[(cb + 1) * OUTD + o], acc);
            acc = fmaf(h.z, om[(cb + 2) * OUTD + o], acc);
            acc = fmaf(h.w, om[(cb + 3) * OUTD + o], acc);
        }
        const float zinv = 1.0f / Zw[i];
        const float logit = acc * zinv + bv;
        out[(size_t)i * OUTD + o] = 1.0f / (1.0f + expf(-logit));
    }
}

extern "C" void kernel_launch(void* const* d_in, const int* in_sizes, int n_in,
                              void* d_out, int out_size, void* d_ws, size_t ws_size,
                              hipStream_t stream) {
    const float* X     = (const float*)d_in[0];
    const int*   A     = (const int*)d_in[1];
    const float* W1    = (const float*)d_in[2];
    const float* b1    = (const float*)d_in[3];
    const float* avec  = (const float*)d_in[4];
    const float* Omega = (const float*)d_in[5];
    const float* beta  = (const float*)d_in[6];
    float* out = (float*)d_out;

    char* ws = (char*)d_ws;
    unsigned short* H1TB = (unsigned short*)(ws + 0);       // 4,194,304
    short* W1Thi = (short*)(ws + 4194304);                  // 262,144
    short* W1Tlo = (short*)(ws + 4456448);                  // 262,144
    float* alw   = (float*)(ws + 4718592);                  // 32,768
    float* bew   = (float*)(ws + 4751360);                  // 32,768
    float* uvw   = (float*)(ws + 4784128);                  // 65,536
    float* Zw    = (float*)(ws + 4849664);                  // 32,768
    float* H2acc = (float*)(ws + 4882432);                  // 8,388,608
    unsigned int* Apk = (unsigned int*)(ws + 13271040);     // 8,388,608 (end 21,659,648)

    k_splitW1<<<512, 256, 0, stream>>>(W1, W1Thi, W1Tlo);
    k_fat<<<2688, 256, 0, stream>>>(X, W1Thi, W1Tlo, b1, avec, H1TB, alw, bew, uvw,
                                    A, Apk, Zw);
    k_attn<<<1024, 256, 0, stream>>>(Apk, H1TB, alw, bew, uvw, H2acc, Zw);
    k_out<<<256, 256, 0, stream>>>(H2acc, Zw, Omega, beta, out);
}